// Round 11
// baseline (2033.148 us; speedup 1.0000x reference)
//
#include <hip/hip_runtime.h>
#include <hip/hip_bf16.h>

#define N_NODES 50000
#define DEG     16
#define IN_CH   128
#define TYPE_DIM 32
#define F_DIM   160      // = IN_CH + TYPE_DIM
#define H_DIM   160
#define OUT_CH  128
#define NSTEP   16       // = DEG timesteps
#define LS      168      // LDS row stride in ushorts (16B-aligned, 2-way-alias only)
#define MB      32       // nodes per block

typedef short  bf16x8 __attribute__((ext_vector_type(8)));
typedef float  f32x4  __attribute__((ext_vector_type(4)));
typedef unsigned int u32x4 __attribute__((ext_vector_type(4)));

// Workspace in __device__ globals (cached VRAM) — R5 proved d_ws is mapped
// uncached/streaming. Fully rewritten every call.
__device__ ushort g_hin[N_NODES * F_DIM];       // 16,000,000 B
__device__ ushort g_wfrag[400 * 64 * 8];        // 409,600 B
__device__ ushort g_wlrfrag[80 * 64 * 8];       // 81,920 B
__device__ float  g_bsum[4 * H_DIM];            // 2,560 B

static __device__ __forceinline__ ushort f2bf(float v) {
    union { float f; unsigned u; } x; x.f = v;
    unsigned r = x.u + 0x7fff + ((x.u >> 16) & 1);   // RNE
    return (ushort)(r >> 16);
}
static __device__ __forceinline__ float sigmoid_fast(float x) {
    return 1.f / (1.f + __expf(-x));
}
static __device__ __forceinline__ float tanh_fast(float x) {
    float e = __expf(2.f * x);
    return 1.f - 2.f / (e + 1.f);
}

// ---------------------------------------------------------------------------
// Pack weights into MFMA B-fragment order (bf16), and sum biases.
// Main W frags: frag = qg*40 + kc*4 + p   (qg 0..9, kc 0..9 K-chunk, p gate i/f/g/o)
//   frag[lane] = 8 bf16 of W[row = p*160 + qg*16 + (lane&15)][k = kcL*32 + (lane>>4)*8 + j]
//   kc<5 -> W_ih (X part), kc>=5 -> W_hh (H part)
// Final W frags: frag = kc*8 + nt : row = nt*16+(lane&15), k<160 -> W_l, else W_r
// ---------------------------------------------------------------------------
__global__ void pack_kernel(const float* __restrict__ Wih, const float* __restrict__ Whh,
                            const float* __restrict__ bih, const float* __restrict__ bhh,
                            const float* __restrict__ Wl,  const float* __restrict__ Wr)
{
    int gid = blockIdx.x * 256 + threadIdx.x;
    if (gid < 400 * 64) {
        int frag = gid >> 6, lane = gid & 63;
        int p = frag & 3, kc = (frag >> 2) % 10, qg = frag / 40;
        int row = p * 160 + qg * 16 + (lane & 15);
        int quad = lane >> 4;
        const float* src; int k0;
        if (kc < 5) { src = Wih + row * 160; k0 = kc * 32 + quad * 8; }
        else        { src = Whh + row * 160; k0 = (kc - 5) * 32 + quad * 8; }
        ushort tmp[8];
        #pragma unroll
        for (int j = 0; j < 8; j++) tmp[j] = f2bf(src[k0 + j]);
        ((u32x4*)g_wfrag)[frag * 64 + lane] = *(const u32x4*)tmp;
    } else if (gid < 400 * 64 + 80 * 64) {
        int g2 = gid - 400 * 64;
        int frag = g2 >> 6, lane = g2 & 63;
        int nt = frag & 7, kc = frag >> 3;
        int row = nt * 16 + (lane & 15);
        int quad = lane >> 4;
        int k0 = kc * 32 + quad * 8;
        ushort tmp[8];
        #pragma unroll
        for (int j = 0; j < 8; j++) {
            int k = k0 + j;
            float v = (k < 160) ? Wl[row * 160 + k] : Wr[row * 160 + (k - 160)];
            tmp[j] = f2bf(v);
        }
        ((u32x4*)g_wlrfrag)[frag * 64 + lane] = *(const u32x4*)tmp;
    } else if (gid < 400 * 64 + 80 * 64 + 640) {
        int i = gid - (400 * 64 + 80 * 64);
        g_bsum[i] = bih[i] + bhh[i];
    }
}

// h_in = concat(x, emb[type]) as bf16 rows of 160 (320 B, 16B aligned)
__global__ void build_hin(const float* __restrict__ x, const int* __restrict__ tids,
                          const float* __restrict__ emb)
{
    int i = blockIdx.x * 256 + threadIdx.x;
    if (i >= N_NODES * F_DIM) return;
    int n = i / F_DIM, d = i - n * F_DIM;
    float v = (d < IN_CH) ? x[n * IN_CH + d] : emb[tids[n] * TYPE_DIM + (d - IN_CH)];
    g_hin[i] = f2bf(v);
}

// ---------------------------------------------------------------------------
// Fused LSTM-aggregation + SAGE linear.
// Block = 32 nodes, 640 threads = 10 waves. Wave wv owns qg group wv
// (16 gate-cols x 4 gates) for all 32 nodes (2 m-tiles).
// Per-wave regs ~= 32 acc + ~65 arch < 102 -> 5 waves/SIMD -> TWO co-resident
// blocks per CU (20 waves): 2 independent barrier domains + 2x latency hiding
// vs R10's single 10-wave block (148 regs -> 3/SIMD -> 1 block, 63% idle).
// Double-buffered Xb/Hb (43KB static LDS), ONE barrier per step; gather for
// t+1 parked in regs during compute, committed to Xb[nxt] before the barrier.
// ---------------------------------------------------------------------------
__launch_bounds__(640, 5)
__global__ void lstm_sage(const int* __restrict__ edge_src,
                          const float* __restrict__ bl,
                          float* __restrict__ out)
{
    constexpr int BSZ = MB * LS;
    __shared__ ushort Xb[2 * BSZ];
    __shared__ ushort Hb[2 * BSZ];

    const int tid  = threadIdx.x;
    const int lane = tid & 63;
    const int wv   = tid >> 6;           // 0..9 = qg group
    const int col  = lane & 15, quad = lane >> 4;
    const int nb   = blockIdx.x * MB;

    float bG4[4];
    #pragma unroll
    for (int p = 0; p < 4; p++) bG4[p] = g_bsum[p * 160 + wv * 16 + col];

    for (int i = tid; i < BSZ; i += 640) Hb[i] = 0;   // Hb[0] = h0 = 0

    float c_st[2][4];
    #pragma unroll
    for (int m = 0; m < 2; m++)
        #pragma unroll
        for (int r = 0; r < 4; r++) c_st[m][r] = 0.f;

    // gather mapping: 32 rows x 20 threads/row, one u32x4 (16B) seg each
    const int grow  = tid / 20;          // 0..31
    const int gpart = tid - grow * 20;   // 0..19
    const int node_g = nb + grow;
    const int own = (node_g < N_NODES ? node_g : 0);
    const int sbase = own * DEG;

    // prime: X_0 -> Xb[0]
    {
        int s = edge_src[sbase];
        const u32x4* sp = (const u32x4*)(g_hin + s * F_DIM);
        ((u32x4*)(Xb + grow * LS))[gpart] = __builtin_nontemporal_load(sp + gpart);
    }
    int snext = edge_src[sbase + 1];

    const int aoff = col * LS + quad * 8;           // A-frag offset within buffer
    const int hoff = quad * 4 * LS + wv * 16 + col; // h-commit base (row quad*4)

    #pragma unroll 1
    for (int t = 0; t < NSTEP; t++) {
        __syncthreads();   // Xb[cur]=X_t, Hb[cur]=h(t-1) visible; nxt buffers free
        const int cur = (t & 1) * BSZ, nxt = ((t & 1) ^ 1) * BSZ;

        // ---- issue gather load for t+1 (t=15 slot: own row for lin_r); park in regs
        const u32x4* sp = (const u32x4*)(g_hin + ((t < NSTEP - 1) ? snext : own) * F_DIM);
        u32x4 P = __builtin_nontemporal_load(sp + gpart);
        snext = edge_src[sbase + ((t + 2 < DEG) ? t + 2 : 0)];

        // ---- compute: gates for 32 nodes, this wave's qg
        f32x4 acc[2][4];
        #pragma unroll
        for (int m = 0; m < 2; m++)
            #pragma unroll
            for (int p = 0; p < 4; p++)
                acc[m][p] = (f32x4){bG4[p], bG4[p], bG4[p], bG4[p]};

        const u32x4* wq = (const u32x4*)g_wfrag + wv * 40 * 64 + lane;
        const ushort* Xc = Xb + cur;
        const ushort* Hc = Hb + cur;
        #pragma unroll
        for (int kc = 0; kc < 10; kc++) {
            bf16x8 bfr[4];
            #pragma unroll
            for (int p = 0; p < 4; p++) {
                u32x4 u = wq[(kc * 4 + p) * 64];
                bfr[p] = *(const bf16x8*)&u;
            }
            const ushort* ab = ((kc < 5) ? (Xc + kc * 32) : (Hc + (kc - 5) * 32)) + aoff;
            bf16x8 afr[2];
            #pragma unroll
            for (int m = 0; m < 2; m++)
                afr[m] = *(const bf16x8*)(ab + m * (16 * LS));
            #pragma unroll
            for (int m = 0; m < 2; m++)
                #pragma unroll
                for (int p = 0; p < 4; p++)
                    acc[m][p] = __builtin_amdgcn_mfma_f32_16x16x32_bf16(
                        afr[m], bfr[p], acc[m][p], 0, 0, 0);
        }

        // ---- elementwise + commit h(t) to Hb[nxt]
        ushort* Hn = Hb + nxt;
        #pragma unroll
        for (int m = 0; m < 2; m++) {
            #pragma unroll
            for (int r = 0; r < 4; r++) {
                float c = sigmoid_fast(acc[m][1][r]) * c_st[m][r]
                        + sigmoid_fast(acc[m][0][r]) * tanh_fast(acc[m][2][r]);
                c_st[m][r] = c;
                float h = sigmoid_fast(acc[m][3][r]) * tanh_fast(c);
                Hn[hoff + (m * 16 + r) * LS] = f2bf(h);
            }
        }

        // ---- commit parked gather to Xb[nxt] (latency was hidden by compute)
        ((u32x4*)(Xb + nxt + grow * LS))[gpart] = P;
    }

    __syncthreads();   // Hb[0]=h(15), Xb[0]=own h_in rows (t=15 wrote nxt=0)

    // out = relu([h_last | h_in] @ [W_l | W_r]^T + b_l)
    // waves 0..7: m = wv&1 (m-tile), pb = (wv>>1)*2 (2 of 8 out col-tiles)
    if (wv < 8) {
        const int m = wv & 1, pb = (wv >> 1) * 2;
        f32x4 acc[2];
        #pragma unroll
        for (int p = 0; p < 2; p++) {
            float b = bl[(pb + p) * 16 + col];
            acc[p] = (f32x4){b, b, b, b};
        }
        const u32x4* wq2 = (const u32x4*)g_wlrfrag + lane;
        #pragma unroll
        for (int kc = 0; kc < 10; kc++) {
            bf16x8 bfr[2];
            #pragma unroll
            for (int p = 0; p < 2; p++) {
                u32x4 u = wq2[(kc * 8 + pb + p) * 64];
                bfr[p] = *(const bf16x8*)&u;
            }
            const ushort* ab = ((kc < 5) ? (Hb + kc * 32) : (Xb + (kc - 5) * 32))
                               + (m * 16 + col) * LS + quad * 8;
            bf16x8 afr = *(const bf16x8*)ab;
            #pragma unroll
            for (int p = 0; p < 2; p++)
                acc[p] = __builtin_amdgcn_mfma_f32_16x16x32_bf16(afr, bfr[p], acc[p], 0, 0, 0);
        }
        #pragma unroll
        for (int p = 0; p < 2; p++) {
            int ocol = (pb + p) * 16 + col;
            #pragma unroll
            for (int r = 0; r < 4; r++) {
                int node = nb + m * 16 + quad * 4 + r;
                if (node < N_NODES) {
                    float v = acc[p][r];
                    out[node * OUT_CH + ocol] = v > 0.f ? v : 0.f;
                }
            }
        }
    }
}

extern "C" void kernel_launch(void* const* d_in, const int* in_sizes, int n_in,
                              void* d_out, int out_size, void* d_ws, size_t ws_size,
                              hipStream_t stream)
{
    const float* x      = (const float*)d_in[0];
    const int*   tids   = (const int*)  d_in[1];
    const int*   esrc   = (const int*)  d_in[2];   // edge_index[0] = src (dst sorted, DEG each)
    const float* emb    = (const float*)d_in[3];
    const float* Wih    = (const float*)d_in[4];
    const float* Whh    = (const float*)d_in[5];
    const float* bih    = (const float*)d_in[6];
    const float* bhh    = (const float*)d_in[7];
    const float* Wl     = (const float*)d_in[8];
    const float* blin   = (const float*)d_in[9];
    const float* Wr     = (const float*)d_in[10];
    float* out = (float*)d_out;

    hipLaunchKernelGGL(pack_kernel, dim3(123), dim3(256), 0, stream,
                       Wih, Whh, bih, bhh, Wl, Wr);
    hipLaunchKernelGGL(build_hin, dim3((N_NODES * F_DIM + 255) / 256), dim3(256), 0, stream,
                       x, tids, emb);
    hipLaunchKernelGGL(lstm_sage, dim3((N_NODES + MB - 1) / MB), dim3(640), 0, stream,
                       esrc, blin, out);
}

// Round 12
// 1510.645 us; speedup vs baseline: 1.3459x; 1.3459x over previous
//
#include <hip/hip_runtime.h>
#include <hip/hip_bf16.h>

#define N_NODES 50000
#define DEG     16
#define IN_CH   128
#define TYPE_DIM 32
#define F_DIM   160      // = IN_CH + TYPE_DIM
#define H_DIM   160
#define OUT_CH  128
#define NSTEP   16       // = DEG timesteps
#define LS      168      // LDS row stride in ushorts (16B-aligned)

typedef short  bf16x8 __attribute__((ext_vector_type(8)));
typedef float  f32x4  __attribute__((ext_vector_type(4)));
typedef unsigned int u32x4 __attribute__((ext_vector_type(4)));

// Workspace in __device__ globals (cached VRAM) — R5 proved d_ws is mapped
// uncached/streaming. Fully rewritten every call.
__device__ ushort g_hin[N_NODES * F_DIM];       // 16,000,000 B
__device__ ushort g_wfrag[400 * 64 * 8];        // 409,600 B
__device__ ushort g_wlrfrag[80 * 64 * 8];       // 81,920 B
__device__ float  g_bsum[4 * H_DIM];            // 2,560 B
__device__ unsigned g_dummy;                    // sink for touch-prefetch DCE guard

static __device__ __forceinline__ ushort f2bf(float v) {
    union { float f; unsigned u; } x; x.f = v;
    unsigned r = x.u + 0x7fff + ((x.u >> 16) & 1);   // RNE
    return (ushort)(r >> 16);
}
static __device__ __forceinline__ float sigmoid_fast(float x) {
    return 1.f / (1.f + __expf(-x));
}
static __device__ __forceinline__ float tanh_fast(float x) {
    float e = __expf(2.f * x);
    return 1.f - 2.f / (e + 1.f);
}

// ---------------------------------------------------------------------------
// Pack weights into MFMA B-fragment order (bf16), and sum biases.
// Main W frags: frag = qg*40 + kc*4 + p   (qg 0..9, kc 0..9 K-chunk, p gate i/f/g/o)
//   frag[lane] = 8 bf16 of W[row = p*160 + qg*16 + (lane&15)][k = kcL*32 + (lane>>4)*8 + j]
//   kc<5 -> W_ih (X part), kc>=5 -> W_hh (H part)
// Final W frags: frag = kc*8 + nt : row = nt*16+(lane&15), k<160 -> W_l, else W_r
// ---------------------------------------------------------------------------
__global__ void pack_kernel(const float* __restrict__ Wih, const float* __restrict__ Whh,
                            const float* __restrict__ bih, const float* __restrict__ bhh,
                            const float* __restrict__ Wl,  const float* __restrict__ Wr)
{
    int gid = blockIdx.x * 256 + threadIdx.x;
    if (gid < 400 * 64) {
        int frag = gid >> 6, lane = gid & 63;
        int p = frag & 3, kc = (frag >> 2) % 10, qg = frag / 40;
        int row = p * 160 + qg * 16 + (lane & 15);
        int quad = lane >> 4;
        const float* src; int k0;
        if (kc < 5) { src = Wih + row * 160; k0 = kc * 32 + quad * 8; }
        else        { src = Whh + row * 160; k0 = (kc - 5) * 32 + quad * 8; }
        ushort tmp[8];
        #pragma unroll
        for (int j = 0; j < 8; j++) tmp[j] = f2bf(src[k0 + j]);
        ((u32x4*)g_wfrag)[frag * 64 + lane] = *(const u32x4*)tmp;
    } else if (gid < 400 * 64 + 80 * 64) {
        int g2 = gid - 400 * 64;
        int frag = g2 >> 6, lane = g2 & 63;
        int nt = frag & 7, kc = frag >> 3;
        int row = nt * 16 + (lane & 15);
        int quad = lane >> 4;
        int k0 = kc * 32 + quad * 8;
        ushort tmp[8];
        #pragma unroll
        for (int j = 0; j < 8; j++) {
            int k = k0 + j;
            float v = (k < 160) ? Wl[row * 160 + k] : Wr[row * 160 + (k - 160)];
            tmp[j] = f2bf(v);
        }
        ((u32x4*)g_wlrfrag)[frag * 64 + lane] = *(const u32x4*)tmp;
    } else if (gid < 400 * 64 + 80 * 64 + 640) {
        int i = gid - (400 * 64 + 80 * 64);
        g_bsum[i] = bih[i] + bhh[i];
    }
}

// h_in = concat(x, emb[type]) as bf16 rows of 160 (320 B, 16B aligned)
__global__ void build_hin(const float* __restrict__ x, const int* __restrict__ tids,
                          const float* __restrict__ emb)
{
    int i = blockIdx.x * 256 + threadIdx.x;
    if (i >= N_NODES * F_DIM) return;
    int n = i / F_DIM, d = i - n * F_DIM;
    float v = (d < IN_CH) ? x[n * IN_CH + d] : emb[tids[n] * TYPE_DIM + (d - IN_CH)];
    g_hin[i] = f2bf(v);
}

// ---------------------------------------------------------------------------
// R10 structure (best so far: 1310us) + WEIGHT TOUCH-PREFETCH:
// after each step's MFMA loop each wave re-touches its own 40KB weight slice
// (10 x 64B-strided dwords/lane). The touch misses overlap the elementwise +
// barrier + gather, so the NEXT step's real fragment loads hit warm L2.
// Discriminates latency-exposed misses (big win) vs miss-BW bound (neutral).
// Block = 64 nodes, 640 threads = 10 waves; wave wv owns qg group wv.
// Double-buffered Xb/Hb, 84KB dynamic LDS, one barrier/step.
// ---------------------------------------------------------------------------
__launch_bounds__(640)
__global__ void lstm_sage_db(const int* __restrict__ edge_src,
                             const float* __restrict__ bl,
                             float* __restrict__ out)
{
    extern __shared__ ushort lds[];
    constexpr int XOFF = 0;            // Xb[0], Xb[1] at XOFF + buf*64*LS
    constexpr int HOFF = 2 * 64 * LS;  // Hb[0], Hb[1] at HOFF + buf*64*LS
    constexpr int BSZ  = 64 * LS;

    const int tid  = threadIdx.x;
    const int lane = tid & 63;
    const int wv   = tid >> 6;           // 0..9 = qg group
    const int col  = lane & 15, quad = lane >> 4;
    const int nb   = blockIdx.x * 64;

    float bG4[4];
    #pragma unroll
    for (int p = 0; p < 4; p++) bG4[p] = g_bsum[p * 160 + wv * 16 + col];

    for (int i = tid; i < BSZ; i += 640) lds[HOFF + i] = 0;   // Hb[0] = h0 = 0

    float c_st[4][4];
    #pragma unroll
    for (int m = 0; m < 4; m++)
        #pragma unroll
        for (int r = 0; r < 4; r++) c_st[m][r] = 0.f;

    const int grow  = tid / 10;          // 64 rows x 10 threads
    const int gpart = tid - grow * 10;   // 0..9 -> segs gpart, gpart+10
    const int node_g = nb + grow;
    const int own = (node_g < N_NODES ? node_g : 0);
    const int sbase = own * DEG;

    // prime: X_0 -> Xb[0]
    {
        int s = edge_src[sbase];
        const u32x4* sp = (const u32x4*)(g_hin + s * F_DIM);
        u32x4* dp = (u32x4*)(lds + XOFF + grow * LS);
        dp[gpart]      = __builtin_nontemporal_load(sp + gpart);
        dp[gpart + 10] = __builtin_nontemporal_load(sp + gpart + 10);
    }
    int snext = edge_src[sbase + 1];

    // per-wave invariant addresses
    const int aoff = col * LS + quad * 8;           // A-frag offset within buffer
    const int hoff = quad * 4 * LS + wv * 16 + col; // h-commit base (row quad*4)

    // touch-prefetch base: this wave's 40KB weight slice, 640B per lane
    const unsigned* tb = (const unsigned*)g_wfrag + wv * 10240 + lane * 160;
    unsigned tch = 0;

    #pragma unroll 1
    for (int t = 0; t < NSTEP; t++) {
        __syncthreads();   // Xb[cur]=X_t and Hb[cur]=h(t-1) visible
        const int cur = (t & 1) * BSZ, nxt = ((t & 1) ^ 1) * BSZ;

        // ---- gather X_{t+1} straight into Xb[nxt] (t=15 slot: own row)
        {
            const u32x4* sp = (const u32x4*)(g_hin + ((t < NSTEP - 1) ? snext : own) * F_DIM);
            u32x4 v0 = __builtin_nontemporal_load(sp + gpart);
            u32x4 v1 = __builtin_nontemporal_load(sp + gpart + 10);
            u32x4* dp = (u32x4*)(lds + XOFF + nxt + grow * LS);
            dp[gpart] = v0; dp[gpart + 10] = v1;
            snext = edge_src[sbase + ((t + 2 < DEG) ? t + 2 : 0)];
        }

        // ---- compute: gates for all 64 nodes, this wave's qg
        f32x4 acc[4][4];
        #pragma unroll
        for (int m = 0; m < 4; m++)
            #pragma unroll
            for (int p = 0; p < 4; p++)
                acc[m][p] = (f32x4){bG4[p], bG4[p], bG4[p], bG4[p]};

        const u32x4* wq = (const u32x4*)g_wfrag + wv * 40 * 64 + lane;
        const ushort* Xc = lds + XOFF + cur;
        const ushort* Hc = lds + HOFF + cur;
        #pragma unroll
        for (int kc = 0; kc < 10; kc++) {
            bf16x8 bfr[4];
            #pragma unroll
            for (int p = 0; p < 4; p++) {
                u32x4 u = wq[(kc * 4 + p) * 64];
                bfr[p] = *(const bf16x8*)&u;
            }
            const ushort* ab = ((kc < 5) ? (Xc + kc * 32) : (Hc + (kc - 5) * 32)) + aoff;
            bf16x8 afr[4];
            #pragma unroll
            for (int m = 0; m < 4; m++)
                afr[m] = *(const bf16x8*)(ab + m * (16 * LS));
            #pragma unroll
            for (int m = 0; m < 4; m++)
                #pragma unroll
                for (int p = 0; p < 4; p++)
                    acc[m][p] = __builtin_amdgcn_mfma_f32_16x16x32_bf16(
                        afr[m], bfr[p], acc[m][p], 0, 0, 0);
        }

        // ---- touch-prefetch: re-warm this wave's weight slice for step t+1.
        // Issued here so the ~L2/HBM latency overlaps elementwise + barrier.
        {
            unsigned s = 0;
            #pragma unroll
            for (int i = 0; i < 10; i++) s ^= tb[i * 16];   // 64B stride
            tch ^= s;
        }

        // ---- elementwise + commit h(t) straight to Hb[nxt]
        ushort* Hn = lds + HOFF + nxt;
        #pragma unroll
        for (int m = 0; m < 4; m++) {
            #pragma unroll
            for (int r = 0; r < 4; r++) {
                float c = sigmoid_fast(acc[m][1][r]) * c_st[m][r]
                        + sigmoid_fast(acc[m][0][r]) * tanh_fast(acc[m][2][r]);
                c_st[m][r] = c;
                float h = sigmoid_fast(acc[m][3][r]) * tanh_fast(c);
                Hn[hoff + (m * 16 + r) * LS] = f2bf(h);
            }
        }
    }

    __syncthreads();   // Hb[0]=h(15), Xb[0]=own h_in rows (t=15 wrote nxt=0)

    if (tid == 0) g_dummy = tch;   // DCE guard for touch loads (harmless store)

    // out = relu([h_last | h_in] @ [W_l | W_r]^T + b_l)
    // waves 0..7: (m = wv&3, phalf = wv>>2); waves 8,9 idle (no barriers after)
    if (wv < 8) {
        const int m = wv & 3, pb = (wv >> 2) * 4;
        f32x4 acc[4];
        #pragma unroll
        for (int p = 0; p < 4; p++) {
            float b = bl[(pb + p) * 16 + col];
            acc[p] = (f32x4){b, b, b, b};
        }
        const u32x4* wq2 = (const u32x4*)g_wlrfrag + lane;
        #pragma unroll
        for (int kc = 0; kc < 10; kc++) {
            bf16x8 bfr[4];
            #pragma unroll
            for (int p = 0; p < 4; p++) {
                u32x4 u = wq2[(kc * 8 + pb + p) * 64];
                bfr[p] = *(const bf16x8*)&u;
            }
            const ushort* ab = ((kc < 5) ? (lds + HOFF + kc * 32) : (lds + XOFF + (kc - 5) * 32))
                               + (m * 16 + col) * LS + quad * 8;
            bf16x8 afr = *(const bf16x8*)ab;
            #pragma unroll
            for (int p = 0; p < 4; p++)
                acc[p] = __builtin_amdgcn_mfma_f32_16x16x32_bf16(afr, bfr[p], acc[p], 0, 0, 0);
        }
        #pragma unroll
        for (int p = 0; p < 4; p++) {
            int ocol = (pb + p) * 16 + col;
            #pragma unroll
            for (int r = 0; r < 4; r++) {
                int node = nb + m * 16 + quad * 4 + r;
                if (node < N_NODES) {
                    float v = acc[p][r];
                    out[node * OUT_CH + ocol] = v > 0.f ? v : 0.f;
                }
            }
        }
    }
}

// ---------------------------------------------------------------------------
// FALLBACK: R8 kernel (static 43KB LDS, 2 barriers/step) — used only if the
// 84KB dynamic-LDS attribute probe fails.
// ---------------------------------------------------------------------------
__launch_bounds__(640)
__global__ void lstm_sage_sb(const int* __restrict__ edge_src,
                             const float* __restrict__ bl,
                             float* __restrict__ out)
{
    __shared__ ushort Xb[64 * LS];
    __shared__ ushort Hb[64 * LS];

    const int tid  = threadIdx.x;
    const int lane = tid & 63;
    const int wv   = tid >> 6;
    const int col  = lane & 15, quad = lane >> 4;
    const int nb   = blockIdx.x * 64;

    float bG4[4];
    #pragma unroll
    for (int p = 0; p < 4; p++) bG4[p] = g_bsum[p * 160 + wv * 16 + col];

    for (int i = tid; i < 64 * LS; i += 640) Hb[i] = 0;

    float c_st[4][4];
    #pragma unroll
    for (int m = 0; m < 4; m++)
        #pragma unroll
        for (int r = 0; r < 4; r++) c_st[m][r] = 0.f;

    unsigned hn[4][2];

    const int grow  = tid / 10;
    const int gpart = tid - grow * 10;
    const int node_g = nb + grow;
    const int sbase = (node_g < N_NODES ? node_g : 0) * DEG;

    u32x4 P0, P1;
    {
        int s = edge_src[sbase];
        const u32x4* sp = (const u32x4*)(g_hin + s * F_DIM);
        P0 = sp[gpart]; P1 = sp[gpart + 10];
    }
    int snext = edge_src[sbase + 1];

    #pragma unroll 1
    for (int t = 0; t < NSTEP; t++) {
        if (t > 0) {
            #pragma unroll
            for (int m = 0; m < 4; m++)
                #pragma unroll
                for (int k = 0; k < 2; k++) {
                    int a = (m * 16 + quad * 4 + 2 * k) * LS + wv * 16 + col;
                    unsigned pk = hn[m][k];
                    Hb[a]      = (ushort)pk;
                    Hb[a + LS] = (ushort)(pk >> 16);
                }
        }
        {
            u32x4* dp = (u32x4*)(Xb + grow * LS);
            dp[gpart] = P0; dp[gpart + 10] = P1;
        }
        __syncthreads();

        {
            const u32x4* sp = (t < NSTEP - 1)
                ? (const u32x4*)(g_hin + snext * F_DIM)
                : (const u32x4*)(g_hin + (node_g < N_NODES ? node_g : 0) * F_DIM);
            P0 = sp[gpart]; P1 = sp[gpart + 10];
            snext = edge_src[sbase + ((t + 2 < DEG) ? t + 2 : 0)];
        }

        f32x4 acc[4][4];
        #pragma unroll
        for (int m = 0; m < 4; m++)
            #pragma unroll
            for (int p = 0; p < 4; p++)
                acc[m][p] = (f32x4){bG4[p], bG4[p], bG4[p], bG4[p]};

        const u32x4* wq = (const u32x4*)g_wfrag + wv * 40 * 64 + lane;
        #pragma unroll
        for (int kc = 0; kc < 10; kc++) {
            bf16x8 bfr[4];
            #pragma unroll
            for (int p = 0; p < 4; p++) {
                u32x4 u = wq[(kc * 4 + p) * 64];
                bfr[p] = *(const bf16x8*)&u;
            }
            const ushort* ab = ((kc < 5) ? (Xb + kc * 32) : (Hb + (kc - 5) * 32))
                               + col * LS + quad * 8;
            bf16x8 afr[4];
            #pragma unroll
            for (int m = 0; m < 4; m++)
                afr[m] = *(const bf16x8*)(ab + m * (16 * LS));
            #pragma unroll
            for (int m = 0; m < 4; m++)
                #pragma unroll
                for (int p = 0; p < 4; p++)
                    acc[m][p] = __builtin_amdgcn_mfma_f32_16x16x32_bf16(
                        afr[m], bfr[p], acc[m][p], 0, 0, 0);
        }
        #pragma unroll
        for (int m = 0; m < 4; m++) {
            #pragma unroll
            for (int k = 0; k < 2; k++) {
                unsigned pk = 0;
                #pragma unroll
                for (int h2 = 0; h2 < 2; h2++) {
                    int r = 2 * k + h2;
                    float c = sigmoid_fast(acc[m][1][r]) * c_st[m][r]
                            + sigmoid_fast(acc[m][0][r]) * tanh_fast(acc[m][2][r]);
                    c_st[m][r] = c;
                    float h = sigmoid_fast(acc[m][3][r]) * tanh_fast(c);
                    pk |= ((unsigned)f2bf(h)) << (16 * h2);
                }
                hn[m][k] = pk;
            }
        }
        __syncthreads();
    }

    #pragma unroll
    for (int m = 0; m < 4; m++)
        #pragma unroll
        for (int k = 0; k < 2; k++) {
            int a = (m * 16 + quad * 4 + 2 * k) * LS + wv * 16 + col;
            unsigned pk = hn[m][k];
            Hb[a]      = (ushort)pk;
            Hb[a + LS] = (ushort)(pk >> 16);
        }
    {
        u32x4* dp = (u32x4*)(Xb + grow * LS);
        dp[gpart] = P0; dp[gpart + 10] = P1;
    }
    __syncthreads();

    if (wv < 8) {
        const int m = wv & 3, pb = (wv >> 2) * 4;
        f32x4 acc[4];
        #pragma unroll
        for (int p = 0; p < 4; p++) {
            float b = bl[(pb + p) * 16 + col];
            acc[p] = (f32x4){b, b, b, b};
        }
        const u32x4* wq2 = (const u32x4*)g_wlrfrag + lane;
        #pragma unroll
        for (int kc = 0; kc < 10; kc++) {
            bf16x8 bfr[4];
            #pragma unroll
            for (int p = 0; p < 4; p++) {
                u32x4 u = wq2[(kc * 8 + pb + p) * 64];
                bfr[p] = *(const bf16x8*)&u;
            }
            const ushort* ab = ((kc < 5) ? (Hb + kc * 32) : (Xb + (kc - 5) * 32))
                               + (m * 16 + col) * LS + quad * 8;
            bf16x8 afr = *(const bf16x8*)ab;
            #pragma unroll
            for (int p = 0; p < 4; p++)
                acc[p] = __builtin_amdgcn_mfma_f32_16x16x32_bf16(afr, bfr[p], acc[p], 0, 0, 0);
        }
        #pragma unroll
        for (int p = 0; p < 4; p++) {
            int ocol = (pb + p) * 16 + col;
            #pragma unroll
            for (int r = 0; r < 4; r++) {
                int node = nb + m * 16 + quad * 4 + r;
                if (node < N_NODES) {
                    float v = acc[p][r];
                    out[node * OUT_CH + ocol] = v > 0.f ? v : 0.f;
                }
            }
        }
    }
}

extern "C" void kernel_launch(void* const* d_in, const int* in_sizes, int n_in,
                              void* d_out, int out_size, void* d_ws, size_t ws_size,
                              hipStream_t stream)
{
    const float* x      = (const float*)d_in[0];
    const int*   tids   = (const int*)  d_in[1];
    const int*   esrc   = (const int*)  d_in[2];   // edge_index[0] = src (dst sorted, DEG each)
    const float* emb    = (const float*)d_in[3];
    const float* Wih    = (const float*)d_in[4];
    const float* Whh    = (const float*)d_in[5];
    const float* bih    = (const float*)d_in[6];
    const float* bhh    = (const float*)d_in[7];
    const float* Wl     = (const float*)d_in[8];
    const float* blin   = (const float*)d_in[9];
    const float* Wr     = (const float*)d_in[10];
    float* out = (float*)d_out;

    hipLaunchKernelGGL(pack_kernel, dim3(123), dim3(256), 0, stream,
                       Wih, Whh, bih, bhh, Wl, Wr);
    hipLaunchKernelGGL(build_hin, dim3((N_NODES * F_DIM + 255) / 256), dim3(256), 0, stream,
                       x, tids, emb);

    const int dbShmem = 4 * 64 * LS * (int)sizeof(ushort);   // 86016 B
    (void)hipFuncSetAttribute((const void*)lstm_sage_db,
                              hipFuncAttributeMaxDynamicSharedMemorySize, dbShmem);
    hipFuncAttributes fa;
    bool dbOk = (hipFuncGetAttributes(&fa, (const void*)lstm_sage_db) == hipSuccess) &&
                (fa.maxDynamicSharedSizeBytes >= dbShmem);

    if (dbOk) {
        hipLaunchKernelGGL(lstm_sage_db, dim3((N_NODES + 63) / 64), dim3(640),
                           dbShmem, stream, esrc, blin, out);
    } else {
        hipLaunchKernelGGL(lstm_sage_sb, dim3((N_NODES + 63) / 64), dim3(640),
                           0, stream, esrc, blin, out);
    }
}

// Round 13
// 1146.451 us; speedup vs baseline: 1.7734x; 1.3177x over previous
//
#include <hip/hip_runtime.h>
#include <hip/hip_bf16.h>

#define N_NODES 50000
#define DEG     16
#define IN_CH   128
#define TYPE_DIM 32
#define F_DIM   160      // = IN_CH + TYPE_DIM
#define H_DIM   160
#define OUT_CH  128
#define NSTEP   16       // = DEG timesteps
#define LS      168      // LDS row stride in ushorts (16B-aligned)

typedef short  bf16x8 __attribute__((ext_vector_type(8)));
typedef float  f32x4  __attribute__((ext_vector_type(4)));
typedef unsigned int u32x4 __attribute__((ext_vector_type(4)));

// Workspace in __device__ globals (cached VRAM) — R5 proved d_ws is mapped
// uncached/streaming. Fully rewritten every call.
__device__ ushort g_hin[N_NODES * F_DIM];       // 16,000,000 B
__device__ ushort g_wfrag[400 * 64 * 8];        // 409,600 B
__device__ ushort g_wlrfrag[80 * 64 * 8];       // 81,920 B
__device__ float  g_bsum[4 * H_DIM];            // 2,560 B

static __device__ __forceinline__ ushort f2bf(float v) {
    union { float f; unsigned u; } x; x.f = v;
    unsigned r = x.u + 0x7fff + ((x.u >> 16) & 1);   // RNE
    return (ushort)(r >> 16);
}
static __device__ __forceinline__ float sigmoid_fast(float x) {
    return 1.f / (1.f + __expf(-x));
}
static __device__ __forceinline__ float tanh_fast(float x) {
    float e = __expf(2.f * x);
    return 1.f - 2.f / (e + 1.f);
}

// ---------------------------------------------------------------------------
// Pack weights into MFMA B-fragment order (bf16), and sum biases.
// Main W frags: frag = qg*40 + kc*4 + p   (qg 0..9, kc 0..9 K-chunk, p gate i/f/g/o)
//   kc<5 -> W_ih (X part), kc>=5 -> W_hh (H part)
// Final W frags: frag = kc*8 + nt : row = nt*16+(lane&15), k<160 -> W_l, else W_r
// ---------------------------------------------------------------------------
__global__ void pack_kernel(const float* __restrict__ Wih, const float* __restrict__ Whh,
                            const float* __restrict__ bih, const float* __restrict__ bhh,
                            const float* __restrict__ Wl,  const float* __restrict__ Wr)
{
    int gid = blockIdx.x * 256 + threadIdx.x;
    if (gid < 400 * 64) {
        int frag = gid >> 6, lane = gid & 63;
        int p = frag & 3, kc = (frag >> 2) % 10, qg = frag / 40;
        int row = p * 160 + qg * 16 + (lane & 15);
        int quad = lane >> 4;
        const float* src; int k0;
        if (kc < 5) { src = Wih + row * 160; k0 = kc * 32 + quad * 8; }
        else        { src = Whh + row * 160; k0 = (kc - 5) * 32 + quad * 8; }
        ushort tmp[8];
        #pragma unroll
        for (int j = 0; j < 8; j++) tmp[j] = f2bf(src[k0 + j]);
        ((u32x4*)g_wfrag)[frag * 64 + lane] = *(const u32x4*)tmp;
    } else if (gid < 400 * 64 + 80 * 64) {
        int g2 = gid - 400 * 64;
        int frag = g2 >> 6, lane = g2 & 63;
        int nt = frag & 7, kc = frag >> 3;
        int row = nt * 16 + (lane & 15);
        int quad = lane >> 4;
        int k0 = kc * 32 + quad * 8;
        ushort tmp[8];
        #pragma unroll
        for (int j = 0; j < 8; j++) {
            int k = k0 + j;
            float v = (k < 160) ? Wl[row * 160 + k] : Wr[row * 160 + (k - 160)];
            tmp[j] = f2bf(v);
        }
        ((u32x4*)g_wlrfrag)[frag * 64 + lane] = *(const u32x4*)tmp;
    } else if (gid < 400 * 64 + 80 * 64 + 640) {
        int i = gid - (400 * 64 + 80 * 64);
        g_bsum[i] = bih[i] + bhh[i];
    }
}

// h_in = concat(x, emb[type]) as bf16 rows of 160 (320 B, 16B aligned)
__global__ void build_hin(const float* __restrict__ x, const int* __restrict__ tids,
                          const float* __restrict__ emb)
{
    int i = blockIdx.x * 256 + threadIdx.x;
    if (i >= N_NODES * F_DIM) return;
    int n = i / F_DIM, d = i - n * F_DIM;
    float v = (d < IN_CH) ? x[n * IN_CH + d] : emb[tids[n] * TYPE_DIM + (d - IN_CH)];
    g_hin[i] = f2bf(v);
}

// ---------------------------------------------------------------------------
// PRIMARY: SPLIT-BARRIER pipeline. Per epoch t (one barrier each):
//   barrier -> issue gather(X(t+2)) [parked in regs, no vmcnt stall]
//           -> H-part MFMA (kc5-9, depends on h(t-1): the ONLY post-barrier dep)
//           -> elementwise -> h(t) -> Hb[(t+1)&1]
//           -> commit parked gather -> Xb[t&1]
//           -> acc=bias; X-part MFMA for t+1 (kc0-4, Xb[(t+1)&1]) PRE-barrier:
//              its weight-load misses overlap other waves' elementwise.
// acc carries bias+Xpart across the barrier in registers.
// Slot algebra: X(t) in Xb[t&1]; every LDS write/read pair has >=1 barrier
// between (write epoch t-2 / read tail of epoch t-1).
// Block = 64 nodes, 640 thr = 10 waves (wave wv owns qg wv); 84KB dyn LDS.
// ---------------------------------------------------------------------------
__launch_bounds__(640)
__global__ void lstm_sage_db(const int* __restrict__ edge_src,
                             const float* __restrict__ bl,
                             float* __restrict__ out)
{
    extern __shared__ ushort lds[];
    constexpr int BSZ  = 64 * LS;
    constexpr int XOFF = 0;            // Xb slots at XOFF + (t&1)*BSZ
    constexpr int HOFF = 2 * BSZ;      // Hb slots at HOFF + (t&1)*BSZ

    const int tid  = threadIdx.x;
    const int lane = tid & 63;
    const int wv   = tid >> 6;           // 0..9 = qg group
    const int col  = lane & 15, quad = lane >> 4;
    const int nb   = blockIdx.x * 64;

    float bG4[4];
    #pragma unroll
    for (int p = 0; p < 4; p++) bG4[p] = g_bsum[p * 160 + wv * 16 + col];

    for (int i = tid; i < BSZ; i += 640) lds[HOFF + i] = 0;   // Hb[0] = h(-1) = 0

    float c_st[4][4];
    #pragma unroll
    for (int m = 0; m < 4; m++)
        #pragma unroll
        for (int r = 0; r < 4; r++) c_st[m][r] = 0.f;

    const int grow  = tid / 10;          // 64 rows x 10 threads
    const int gpart = tid - grow * 10;   // 0..9 -> segs gpart, gpart+10
    const int node_g = nb + grow;
    const int own = (node_g < N_NODES ? node_g : 0);
    const int sbase = own * DEG;

    // prologue: gather X(0) -> slot0, X(1) -> slot1
    {
        int s0 = edge_src[sbase + 0];
        int s1 = edge_src[sbase + 1];
        const u32x4* sp0 = (const u32x4*)(g_hin + s0 * F_DIM);
        const u32x4* sp1 = (const u32x4*)(g_hin + s1 * F_DIM);
        u32x4* d0 = (u32x4*)(lds + XOFF + grow * LS);
        u32x4* d1 = (u32x4*)(lds + XOFF + BSZ + grow * LS);
        d0[gpart]      = __builtin_nontemporal_load(sp0 + gpart);
        d0[gpart + 10] = __builtin_nontemporal_load(sp0 + gpart + 10);
        d1[gpart]      = __builtin_nontemporal_load(sp1 + gpart);
        d1[gpart + 10] = __builtin_nontemporal_load(sp1 + gpart + 10);
    }
    int snext = edge_src[sbase + 2];

    const int aoff = col * LS + quad * 8;           // A-frag offset within buffer
    const int hoff = quad * 4 * LS + wv * 16 + col; // h-commit base (row quad*4)
    const u32x4* wq = (const u32x4*)g_wfrag + wv * 40 * 64 + lane;

    __syncthreads();   // X(0), X(1) visible

    // acc = bias + X-part(0)
    f32x4 acc[4][4];
    #pragma unroll
    for (int m = 0; m < 4; m++)
        #pragma unroll
        for (int p = 0; p < 4; p++)
            acc[m][p] = (f32x4){bG4[p], bG4[p], bG4[p], bG4[p]};
    #pragma unroll
    for (int kx = 0; kx < 5; kx++) {
        bf16x8 bfr[4];
        #pragma unroll
        for (int p = 0; p < 4; p++) {
            u32x4 u = wq[(kx * 4 + p) * 64];
            bfr[p] = *(const bf16x8*)&u;
        }
        const ushort* ab = lds + XOFF + kx * 32 + aoff;   // slot 0
        bf16x8 afr[4];
        #pragma unroll
        for (int m = 0; m < 4; m++)
            afr[m] = *(const bf16x8*)(ab + m * (16 * LS));
        #pragma unroll
        for (int m = 0; m < 4; m++)
            #pragma unroll
            for (int p = 0; p < 4; p++)
                acc[m][p] = __builtin_amdgcn_mfma_f32_16x16x32_bf16(
                    afr[m], bfr[p], acc[m][p], 0, 0, 0);
    }

    #pragma unroll 1
    for (int t = 0; t < NSTEP; t++) {
        __syncthreads();   // barrier t: Hb[t&1]=h(t-1), Xb[(t+1)&1]=X(t+1) visible
        const int cur = (t & 1) * BSZ, nxt = ((t & 1) ^ 1) * BSZ;

        // ---- issue gather for X(t+2) (t=14: own row); PARK in regs (no commit)
        u32x4 P0, P1;
        if (t < NSTEP - 1) {
            const u32x4* sp = (const u32x4*)(g_hin + ((t < NSTEP - 2) ? snext : own) * F_DIM);
            P0 = __builtin_nontemporal_load(sp + gpart);
            P1 = __builtin_nontemporal_load(sp + gpart + 10);
            snext = edge_src[sbase + ((t + 3 < DEG) ? t + 3 : 0)];
        }

        // ---- H-part MFMA: kc 5..9 on Hb[cur] (the only h(t-1)-dependent work)
        const ushort* Hc = lds + HOFF + cur;
        #pragma unroll
        for (int kh = 0; kh < 5; kh++) {
            bf16x8 bfr[4];
            #pragma unroll
            for (int p = 0; p < 4; p++) {
                u32x4 u = wq[((5 + kh) * 4 + p) * 64];
                bfr[p] = *(const bf16x8*)&u;
            }
            const ushort* ab = Hc + kh * 32 + aoff;
            bf16x8 afr[4];
            #pragma unroll
            for (int m = 0; m < 4; m++)
                afr[m] = *(const bf16x8*)(ab + m * (16 * LS));
            #pragma unroll
            for (int m = 0; m < 4; m++)
                #pragma unroll
                for (int p = 0; p < 4; p++)
                    acc[m][p] = __builtin_amdgcn_mfma_f32_16x16x32_bf16(
                        afr[m], bfr[p], acc[m][p], 0, 0, 0);
        }

        // ---- elementwise + commit h(t) to Hb[nxt]
        ushort* Hn = lds + HOFF + nxt;
        #pragma unroll
        for (int m = 0; m < 4; m++) {
            #pragma unroll
            for (int r = 0; r < 4; r++) {
                float c = sigmoid_fast(acc[m][1][r]) * c_st[m][r]
                        + sigmoid_fast(acc[m][0][r]) * tanh_fast(acc[m][2][r]);
                c_st[m][r] = c;
                float h = sigmoid_fast(acc[m][3][r]) * tanh_fast(c);
                Hn[hoff + (m * 16 + r) * LS] = f2bf(h);
            }
        }

        if (t < NSTEP - 1) {
            // ---- commit parked gather: X(t+2) -> Xb[t&1]  ((t+2)&1 == t&1)
            {
                u32x4* dp = (u32x4*)(lds + XOFF + cur + grow * LS);
                dp[gpart] = P0; dp[gpart + 10] = P1;
            }
            // ---- PRE-barrier X-part for t+1: kc 0..4 on Xb[(t+1)&1]
            #pragma unroll
            for (int m = 0; m < 4; m++)
                #pragma unroll
                for (int p = 0; p < 4; p++)
                    acc[m][p] = (f32x4){bG4[p], bG4[p], bG4[p], bG4[p]};
            const ushort* Xn = lds + XOFF + nxt;
            #pragma unroll
            for (int kx = 0; kx < 5; kx++) {
                bf16x8 bfr[4];
                #pragma unroll
                for (int p = 0; p < 4; p++) {
                    u32x4 u = wq[(kx * 4 + p) * 64];
                    bfr[p] = *(const bf16x8*)&u;
                }
                const ushort* ab = Xn + kx * 32 + aoff;
                bf16x8 afr[4];
                #pragma unroll
                for (int m = 0; m < 4; m++)
                    afr[m] = *(const bf16x8*)(ab + m * (16 * LS));
                #pragma unroll
                for (int m = 0; m < 4; m++)
                    #pragma unroll
                    for (int p = 0; p < 4; p++)
                        acc[m][p] = __builtin_amdgcn_mfma_f32_16x16x32_bf16(
                            afr[m], bfr[p], acc[m][p], 0, 0, 0);
            }
        }
    }

    __syncthreads();   // Hb[0]=h(15); Xb[0]=own h_in rows (committed at t=14)

    // out = relu([h_last | h_in] @ [W_l | W_r]^T + b_l)
    // waves 0..7: (m = wv&3, phalf = wv>>2); waves 8,9 idle (no barriers after)
    if (wv < 8) {
        const int m = wv & 3, pb = (wv >> 2) * 4;
        f32x4 acc2[4];
        #pragma unroll
        for (int p = 0; p < 4; p++) {
            float b = bl[(pb + p) * 16 + col];
            acc2[p] = (f32x4){b, b, b, b};
        }
        const u32x4* wq2 = (const u32x4*)g_wlrfrag + lane;
        #pragma unroll
        for (int kc = 0; kc < 10; kc++) {
            bf16x8 bfr[4];
            #pragma unroll
            for (int p = 0; p < 4; p++) {
                u32x4 u = wq2[(kc * 8 + pb + p) * 64];
                bfr[p] = *(const bf16x8*)&u;
            }
            const ushort* ab = ((kc < 5) ? (lds + HOFF + kc * 32) : (lds + XOFF + (kc - 5) * 32))
                               + (m * 16 + col) * LS + quad * 8;
            bf16x8 afr = *(const bf16x8*)ab;
            #pragma unroll
            for (int p = 0; p < 4; p++)
                acc2[p] = __builtin_amdgcn_mfma_f32_16x16x32_bf16(afr, bfr[p], acc2[p], 0, 0, 0);
        }
        #pragma unroll
        for (int p = 0; p < 4; p++) {
            int ocol = (pb + p) * 16 + col;
            #pragma unroll
            for (int r = 0; r < 4; r++) {
                int node = nb + m * 16 + quad * 4 + r;
                if (node < N_NODES) {
                    float v = acc2[p][r];
                    out[node * OUT_CH + ocol] = v > 0.f ? v : 0.f;
                }
            }
        }
    }
}

// ---------------------------------------------------------------------------
// FALLBACK: R8 kernel (static 43KB LDS, 2 barriers/step) — used only if the
// 84KB dynamic-LDS attribute probe fails.
// ---------------------------------------------------------------------------
__launch_bounds__(640)
__global__ void lstm_sage_sb(const int* __restrict__ edge_src,
                             const float* __restrict__ bl,
                             float* __restrict__ out)
{
    __shared__ ushort Xb[64 * LS];
    __shared__ ushort Hb[64 * LS];

    const int tid  = threadIdx.x;
    const int lane = tid & 63;
    const int wv   = tid >> 6;
    const int col  = lane & 15, quad = lane >> 4;
    const int nb   = blockIdx.x * 64;

    float bG4[4];
    #pragma unroll
    for (int p = 0; p < 4; p++) bG4[p] = g_bsum[p * 160 + wv * 16 + col];

    for (int i = tid; i < 64 * LS; i += 640) Hb[i] = 0;

    float c_st[4][4];
    #pragma unroll
    for (int m = 0; m < 4; m++)
        #pragma unroll
        for (int r = 0; r < 4; r++) c_st[m][r] = 0.f;

    unsigned hn[4][2];

    const int grow  = tid / 10;
    const int gpart = tid - grow * 10;
    const int node_g = nb + grow;
    const int sbase = (node_g < N_NODES ? node_g : 0) * DEG;

    u32x4 P0, P1;
    {
        int s = edge_src[sbase];
        const u32x4* sp = (const u32x4*)(g_hin + s * F_DIM);
        P0 = sp[gpart]; P1 = sp[gpart + 10];
    }
    int snext = edge_src[sbase + 1];

    #pragma unroll 1
    for (int t = 0; t < NSTEP; t++) {
        if (t > 0) {
            #pragma unroll
            for (int m = 0; m < 4; m++)
                #pragma unroll
                for (int k = 0; k < 2; k++) {
                    int a = (m * 16 + quad * 4 + 2 * k) * LS + wv * 16 + col;
                    unsigned pk = hn[m][k];
                    Hb[a]      = (ushort)pk;
                    Hb[a + LS] = (ushort)(pk >> 16);
                }
        }
        {
            u32x4* dp = (u32x4*)(Xb + grow * LS);
            dp[gpart] = P0; dp[gpart + 10] = P1;
        }
        __syncthreads();

        {
            const u32x4* sp = (t < NSTEP - 1)
                ? (const u32x4*)(g_hin + snext * F_DIM)
                : (const u32x4*)(g_hin + (node_g < N_NODES ? node_g : 0) * F_DIM);
            P0 = sp[gpart]; P1 = sp[gpart + 10];
            snext = edge_src[sbase + ((t + 2 < DEG) ? t + 2 : 0)];
        }

        f32x4 acc[4][4];
        #pragma unroll
        for (int m = 0; m < 4; m++)
            #pragma unroll
            for (int p = 0; p < 4; p++)
                acc[m][p] = (f32x4){bG4[p], bG4[p], bG4[p], bG4[p]};

        const u32x4* wq = (const u32x4*)g_wfrag + wv * 40 * 64 + lane;
        #pragma unroll
        for (int kc = 0; kc < 10; kc++) {
            bf16x8 bfr[4];
            #pragma unroll
            for (int p = 0; p < 4; p++) {
                u32x4 u = wq[(kc * 4 + p) * 64];
                bfr[p] = *(const bf16x8*)&u;
            }
            const ushort* ab = ((kc < 5) ? (Xb + kc * 32) : (Hb + (kc - 5) * 32))
                               + col * LS + quad * 8;
            bf16x8 afr[4];
            #pragma unroll
            for (int m = 0; m < 4; m++)
                afr[m] = *(const bf16x8*)(ab + m * (16 * LS));
            #pragma unroll
            for (int m = 0; m < 4; m++)
                #pragma unroll
                for (int p = 0; p < 4; p++)
                    acc[m][p] = __builtin_amdgcn_mfma_f32_16x16x32_bf16(
                        afr[m], bfr[p], acc[m][p], 0, 0, 0);
        }
        #pragma unroll
        for (int m = 0; m < 4; m++) {
            #pragma unroll
            for (int k = 0; k < 2; k++) {
                unsigned pk = 0;
                #pragma unroll
                for (int h2 = 0; h2 < 2; h2++) {
                    int r = 2 * k + h2;
                    float c = sigmoid_fast(acc[m][1][r]) * c_st[m][r]
                            + sigmoid_fast(acc[m][0][r]) * tanh_fast(acc[m][2][r]);
                    c_st[m][r] = c;
                    float h = sigmoid_fast(acc[m][3][r]) * tanh_fast(c);
                    pk |= ((unsigned)f2bf(h)) << (16 * h2);
                }
                hn[m][k] = pk;
            }
        }
        __syncthreads();
    }

    #pragma unroll
    for (int m = 0; m < 4; m++)
        #pragma unroll
        for (int k = 0; k < 2; k++) {
            int a = (m * 16 + quad * 4 + 2 * k) * LS + wv * 16 + col;
            unsigned pk = hn[m][k];
            Hb[a]      = (ushort)pk;
            Hb[a + LS] = (ushort)(pk >> 16);
        }
    {
        u32x4* dp = (u32x4*)(Xb + grow * LS);
        dp[gpart] = P0; dp[gpart + 10] = P1;
    }
    __syncthreads();

    if (wv < 8) {
        const int m = wv & 3, pb = (wv >> 2) * 4;
        f32x4 acc[4];
        #pragma unroll
        for (int p = 0; p < 4; p++) {
            float b = bl[(pb + p) * 16 + col];
            acc[p] = (f32x4){b, b, b, b};
        }
        const u32x4* wq2 = (const u32x4*)g_wlrfrag + lane;
        #pragma unroll
        for (int kc = 0; kc < 10; kc++) {
            bf16x8 bfr[4];
            #pragma unroll
            for (int p = 0; p < 4; p++) {
                u32x4 u = wq2[(kc * 8 + pb + p) * 64];
                bfr[p] = *(const bf16x8*)&u;
            }
            const ushort* ab = ((kc < 5) ? (Hb + kc * 32) : (Xb + (kc - 5) * 32))
                               + (m * 16 + col) * LS + quad * 8;
            bf16x8 afr = *(const bf16x8*)ab;
            #pragma unroll
            for (int p = 0; p < 4; p++)
                acc[p] = __builtin_amdgcn_mfma_f32_16x16x32_bf16(afr, bfr[p], acc[p], 0, 0, 0);
        }
        #pragma unroll
        for (int p = 0; p < 4; p++) {
            int ocol = (pb + p) * 16 + col;
            #pragma unroll
            for (int r = 0; r < 4; r++) {
                int node = nb + m * 16 + quad * 4 + r;
                if (node < N_NODES) {
                    float v = acc[p][r];
                    out[node * OUT_CH + ocol] = v > 0.f ? v : 0.f;
                }
            }
        }
    }
}

extern "C" void kernel_launch(void* const* d_in, const int* in_sizes, int n_in,
                              void* d_out, int out_size, void* d_ws, size_t ws_size,
                              hipStream_t stream)
{
    const float* x      = (const float*)d_in[0];
    const int*   tids   = (const int*)  d_in[1];
    const int*   esrc   = (const int*)  d_in[2];   // edge_index[0] = src (dst sorted, DEG each)
    const float* emb    = (const float*)d_in[3];
    const float* Wih    = (const float*)d_in[4];
    const float* Whh    = (const float*)d_in[5];
    const float* bih    = (const float*)d_in[6];
    const float* bhh    = (const float*)d_in[7];
    const float* Wl     = (const float*)d_in[8];
    const float* blin   = (const float*)d_in[9];
    const float* Wr     = (const float*)d_in[10];
    float* out = (float*)d_out;

    hipLaunchKernelGGL(pack_kernel, dim3(123), dim3(256), 0, stream,
                       Wih, Whh, bih, bhh, Wl, Wr);
    hipLaunchKernelGGL(build_hin, dim3((N_NODES * F_DIM + 255) / 256), dim3(256), 0, stream,
                       x, tids, emb);

    const int dbShmem = 4 * 64 * LS * (int)sizeof(ushort);   // 86016 B
    (void)hipFuncSetAttribute((const void*)lstm_sage_db,
                              hipFuncAttributeMaxDynamicSharedMemorySize, dbShmem);
    hipFuncAttributes fa;
    bool dbOk = (hipFuncGetAttributes(&fa, (const void*)lstm_sage_db) == hipSuccess) &&
                (fa.maxDynamicSharedSizeBytes >= dbShmem);

    if (dbOk) {
        hipLaunchKernelGGL(lstm_sage_db, dim3((N_NODES + 63) / 64), dim3(640),
                           dbShmem, stream, esrc, blin, out);
    } else {
        hipLaunchKernelGGL(lstm_sage_sb, dim3((N_NODES + 63) / 64), dim3(640),
                           0, stream, esrc, blin, out);
    }
}